// Round 1
// baseline (608.609 us; speedup 1.0000x reference)
//
#include <hip/hip_runtime.h>
#include <hip/hip_bf16.h>
#include <math.h>

#define B_ROWS 1024
#define V_COLS 50257
#define E_DIM  128
#define BN     64
#define NVB    ((V_COLS + BN - 1) / BN)   // 786

typedef __attribute__((ext_vector_type(8))) short short8;
typedef __attribute__((ext_vector_type(4))) float floatx4;

static __device__ __forceinline__ unsigned short f2bf(float x) {
    union { float f; unsigned int u; } c; c.f = x;
    unsigned int u = c.u;
    unsigned int r = u + 0x7fffu + ((u >> 16) & 1u);
    return (unsigned short)(r >> 16);
}

// ---------------------------------------------------------------- find one-hot index
__global__ void find_idx_kernel(const float4* __restrict__ xs4, int* __restrict__ idx) {
    long i = (long)blockIdx.x * blockDim.x + threadIdx.x;
    const long n4 = (long)B_ROWS * V_COLS / 4;
    if (i >= n4) return;
    float4 v = xs4[i];
    float vals[4] = {v.x, v.y, v.z, v.w};
    #pragma unroll
    for (int c = 0; c < 4; ++c) {
        if (vals[c] != 0.0f) {
            long f = 4 * i + c;
            int b = (int)(f / V_COLS);
            idx[b] = (int)(f - (long)b * V_COLS);
        }
    }
}

// ---------------------------------------------------------------- NEG fp32 -> bf16
__global__ void cvt_bf16_kernel(const float4* __restrict__ src, ushort4* __restrict__ dst, int n4) {
    int i = blockIdx.x * blockDim.x + threadIdx.x;
    if (i >= n4) return;
    float4 v = src[i];
    ushort4 o;
    o.x = f2bf(v.x); o.y = f2bf(v.y); o.z = f2bf(v.z); o.w = f2bf(v.w);
    dst[i] = o;
}

// ---------------------------------------------------------------- t[b] = EMBEDM[idx[b]] @ metric  (bf16 out)
__global__ void compute_t_kernel(const float* __restrict__ EMB, const float* __restrict__ metric,
                                 const int* __restrict__ idx, unsigned short* __restrict__ t) {
    __shared__ float erow[E_DIM];
    int b = blockIdx.x, tid = threadIdx.x;
    int id = idx[b];
    erow[tid] = EMB[(long)id * E_DIM + tid];
    __syncthreads();
    float acc = 0.f;
    #pragma unroll 16
    for (int k = 0; k < E_DIM; ++k) acc += erow[k] * metric[k * E_DIM + tid];
    t[b * E_DIM + tid] = f2bf(acc);
}

// ---------------------------------------------------------------- GEMM scores = t @ NEG^T (MFMA), fused softmax stats / output
// block = 256 threads = 4 waves; block tile BM=64 (wave m-tile 16) x BN=64 (4 n-tiles/wave)
template <bool WRITE_OUT>
__global__ __launch_bounds__(256) void gemm_kernel(const unsigned short* __restrict__ t,
                                                   const unsigned short* __restrict__ neg,
                                                   float2* __restrict__ partials,
                                                   const float* __restrict__ lse,
                                                   float* __restrict__ out) {
    int wave = threadIdx.x >> 6;
    int lane = threadIdx.x & 63;
    int quad = lane >> 4;
    int l16  = lane & 15;
    int mbase = blockIdx.y * 64;
    int nbase = blockIdx.x * 64;
    int mrow  = mbase + wave * 16 + l16;
    int kq    = quad * 8;

    const short8 zero8 = {0,0,0,0,0,0,0,0};
    floatx4 acc[4] = {{0,0,0,0},{0,0,0,0},{0,0,0,0},{0,0,0,0}};

    int nrow[4];
    #pragma unroll
    for (int nt = 0; nt < 4; ++nt) nrow[nt] = nbase + nt * 16 + l16;

    #pragma unroll
    for (int ks = 0; ks < 4; ++ks) {
        short8 a = *(const short8*)(t + (long)mrow * E_DIM + ks * 32 + kq);
        #pragma unroll
        for (int nt = 0; nt < 4; ++nt) {
            short8 bf = (nrow[nt] < V_COLS)
                        ? *(const short8*)(neg + (long)nrow[nt] * E_DIM + ks * 32 + kq)
                        : zero8;
            acc[nt] = __builtin_amdgcn_mfma_f32_16x16x32_bf16(a, bf, acc[nt], 0, 0, 0);
        }
    }

    // C/D layout: row = quad*4 + reg, col = lane&15  [m89-verified]
    __shared__ float sc[64][65];
    #pragma unroll
    for (int nt = 0; nt < 4; ++nt)
        #pragma unroll
        for (int r = 0; r < 4; ++r)
            sc[wave * 16 + quad * 4 + r][nt * 16 + l16] = acc[nt][r];
    __syncthreads();

    if (!WRITE_OUT) {
        int nvalid = V_COLS - nbase; if (nvalid > 64) nvalid = 64;
        if (threadIdx.x < 64) {
            int r = threadIdx.x;
            float m = -INFINITY;
            for (int c = 0; c < nvalid; ++c) m = fmaxf(m, sc[r][c]);
            float s = 0.f;
            for (int c = 0; c < nvalid; ++c) s += __expf(sc[r][c] - m);
            partials[(long)(mbase + r) * NVB + blockIdx.x] = make_float2(m, s);
        }
    } else {
        __shared__ float lsev[64];
        if (threadIdx.x < 64) lsev[threadIdx.x] = lse[mbase + threadIdx.x];
        __syncthreads();
        for (int i = threadIdx.x; i < 64 * 64; i += 256) {
            int r = i >> 6, c = i & 63;
            int col = nbase + c;
            if (col < V_COLS)
                out[(long)(mbase + r) * V_COLS + col] = sc[r][c] - lsev[r];
        }
    }
}

// ---------------------------------------------------------------- merge per-block (m,s) partials -> lse[b]
__global__ void merge_lse_kernel(const float2* __restrict__ partials, float* __restrict__ lse) {
    int b = blockIdx.x;
    int tid = threadIdx.x;
    float m = -INFINITY, s = 0.f;
    for (int i = tid; i < NVB; i += 256) {
        float2 p = partials[(long)b * NVB + i];
        if (p.x > m) { s = s * __expf(m - p.x) + p.y; m = p.x; }
        else         { s += p.y * __expf(p.x - m); }
    }
    __shared__ float sm[256], ss[256];
    sm[tid] = m; ss[tid] = s;
    __syncthreads();
    for (int off = 128; off > 0; off >>= 1) {
        if (tid < off) {
            float m1 = sm[tid], s1 = ss[tid];
            float m2 = sm[tid + off], s2 = ss[tid + off];
            float mm = fmaxf(m1, m2);
            sm[tid] = mm;
            ss[tid] = s1 * __expf(m1 - mm) + s2 * __expf(m2 - mm);
        }
        __syncthreads();
    }
    if (tid == 0) lse[b] = sm[0] + __logf(ss[0]);
}

// ---------------------------------------------------------------- launch
extern "C" void kernel_launch(void* const* d_in, const int* in_sizes, int n_in,
                              void* d_out, int out_size, void* d_ws, size_t ws_size,
                              hipStream_t stream) {
    const float* xs     = (const float*)d_in[0];
    const float* metric = (const float*)d_in[1];
    const float* EMB    = (const float*)d_in[2];
    const float* NEG    = (const float*)d_in[3];
    float* out = (float*)d_out;

    char* ws = (char*)d_ws;
    // layout: idx[1024] | t bf16[1024*128] | neg bf16[50257*128] | partials float2[1024*786] | lse[1024]
    int*            idx      = (int*)ws;                               // 4096 B
    unsigned short* t        = (unsigned short*)(ws + 4096);           // 262144 B -> 266240
    unsigned short* neg16    = (unsigned short*)(ws + 266240);         // 12865792 B -> 13132032
    float2*         partials = (float2*)(ws + 13132032);               // 6438912 B -> 19570944
    float*          lse      = (float*)(ws + 19570944);                // 4096 B

    {
        long n4 = (long)B_ROWS * V_COLS / 4;
        int blocks = (int)((n4 + 255) / 256);
        find_idx_kernel<<<blocks, 256, 0, stream>>>((const float4*)xs, idx);
    }
    {
        int n4 = V_COLS * E_DIM / 4;
        int blocks = (n4 + 255) / 256;
        cvt_bf16_kernel<<<blocks, 256, 0, stream>>>((const float4*)NEG, (ushort4*)neg16, n4);
    }
    compute_t_kernel<<<B_ROWS, E_DIM, 0, stream>>>(EMB, metric, idx, t);
    gemm_kernel<false><<<dim3(NVB, B_ROWS / 64), 256, 0, stream>>>(t, neg16, partials, nullptr, nullptr);
    merge_lse_kernel<<<B_ROWS, 256, 0, stream>>>(partials, lse);
    gemm_kernel<true><<<dim3(NVB, B_ROWS / 64), 256, 0, stream>>>(t, neg16, partials, lse, out);
}

// Round 2
// 467.029 us; speedup vs baseline: 1.3031x; 1.3031x over previous
//
#include <hip/hip_runtime.h>
#include <hip/hip_bf16.h>
#include <math.h>

#define B_ROWS 1024
#define V_COLS 50257
#define E_DIM  128
#define BM     128
#define BN     128
#define NNB    393                 // ceil(V_COLS / BN)
#define VPAD   (NNB * BN)          // 50304
#define N4     (V_COLS * E_DIM / 4)   // 1608224
#define N4P    (VPAD * E_DIM / 4)     // 1609728

typedef __attribute__((ext_vector_type(8))) short short8;
typedef __attribute__((ext_vector_type(4))) float floatx4;

static __device__ __forceinline__ unsigned short f2bf(float x) {
    union { float f; unsigned int u; } c; c.f = x;
    unsigned int u = c.u;
    unsigned int r = u + 0x7fffu + ((u >> 16) & 1u);
    return (unsigned short)(r >> 16);
}

// ---------------------------------------------------------------- find one-hot index
__global__ void find_idx_kernel(const float4* __restrict__ xs4, int* __restrict__ idx) {
    long i = (long)blockIdx.x * blockDim.x + threadIdx.x;
    const long n4 = (long)B_ROWS * V_COLS / 4;
    if (i >= n4) return;
    float4 v = xs4[i];
    float vals[4] = {v.x, v.y, v.z, v.w};
    #pragma unroll
    for (int c = 0; c < 4; ++c) {
        if (vals[c] != 0.0f) {
            long f = 4 * i + c;
            int b = (int)(f / V_COLS);
            idx[b] = (int)(f - (long)b * V_COLS);
        }
    }
}

// ---------------------------------------------------------------- NEG fp32 -> bf16 (padded to VPAD rows, zeros)
__global__ void cvt_bf16_kernel(const float4* __restrict__ src, ushort4* __restrict__ dst) {
    int i = blockIdx.x * blockDim.x + threadIdx.x;
    if (i >= N4P) return;
    ushort4 o;
    if (i < N4) {
        float4 v = src[i];
        o.x = f2bf(v.x); o.y = f2bf(v.y); o.z = f2bf(v.z); o.w = f2bf(v.w);
    } else {
        o.x = 0; o.y = 0; o.z = 0; o.w = 0;
    }
    dst[i] = o;
}

// ---------------------------------------------------------------- t[b] = EMBEDM[idx[b]] @ metric  (bf16 out)
__global__ void compute_t_kernel(const float* __restrict__ EMB, const float* __restrict__ metric,
                                 const int* __restrict__ idx, unsigned short* __restrict__ t) {
    __shared__ float erow[E_DIM];
    int b = blockIdx.x, tid = threadIdx.x;
    int id = idx[b];
    erow[tid] = EMB[(long)id * E_DIM + tid];
    __syncthreads();
    float acc = 0.f;
    #pragma unroll 16
    for (int k = 0; k < E_DIM; ++k) acc += erow[k] * metric[k * E_DIM + tid];
    t[b * E_DIM + tid] = f2bf(acc);
}

// ---------------------------------------------------------------- tiled MFMA GEMM: scores = t @ neg^T
// 128x128 block tile, 256 threads = 4 waves (2x2), K=128 single LDS stage.
// LDS layout: 16B chunks, chunk position XOR-swizzled by (row&15) -> conflict-floor reads/writes.
template <bool WRITE_OUT>
__global__ __launch_bounds__(256) void gemm_kernel(const unsigned short* __restrict__ t,
                                                   const unsigned short* __restrict__ neg,
                                                   float2* __restrict__ partials,
                                                   const float* __restrict__ lse,
                                                   float* __restrict__ out) {
    __shared__ __align__(16) unsigned char smem[128 * 132 * 4]; // 67584 B: tiles (64KB) then score buf
    __shared__ float2 stats[2][128];
    __shared__ float lsev[128];

    const int tid  = threadIdx.x;
    const int lane = tid & 63, wave = tid >> 6;
    const int l16  = lane & 15, q = lane >> 4;
    const int wm   = wave >> 1, wn = wave & 1;
    const int mbase = blockIdx.y * BM;
    const int nbase = blockIdx.x * BN;

    if (WRITE_OUT && tid < 128) lsev[tid] = lse[mbase + tid];

    // ---- stage A (t rows) and B (neg rows) into LDS, coalesced + swizzled
    uint4* ldsA = (uint4*)smem;
    uint4* ldsB = (uint4*)(smem + 32768);
    const uint4* srcA = (const uint4*)(t + (size_t)mbase * E_DIM);
    const uint4* srcB = (const uint4*)(neg + (size_t)nbase * E_DIM);
    #pragma unroll
    for (int it = 0; it < 8; ++it) {
        int idx = it * 256 + tid;              // 0..2047 : row=idx>>4, chunk=idx&15
        int r = idx >> 4, c = idx & 15;
        int d = (r << 4) + (c ^ (r & 15));
        ldsA[d] = srcA[idx];
        ldsB[d] = srcB[idx];
    }
    __syncthreads();

    // ---- MFMA: each wave computes 64x64 (4x4 frags of 16x16x32)
    floatx4 acc[4][4];
    #pragma unroll
    for (int i = 0; i < 4; ++i)
        #pragma unroll
        for (int j = 0; j < 4; ++j) acc[i][j] = (floatx4){0, 0, 0, 0};

    #pragma unroll
    for (int ks = 0; ks < 4; ++ks) {
        short8 af[4], bfr[4];
        #pragma unroll
        for (int mf = 0; mf < 4; ++mf) {
            int row = wm * 64 + mf * 16 + l16;
            af[mf] = *(const short8*)&ldsA[(row << 4) + ((ks * 4 + q) ^ (row & 15))];
        }
        #pragma unroll
        for (int nt = 0; nt < 4; ++nt) {
            int row = wn * 64 + nt * 16 + l16;
            bfr[nt] = *(const short8*)&ldsB[(row << 4) + ((ks * 4 + q) ^ (row & 15))];
        }
        #pragma unroll
        for (int mf = 0; mf < 4; ++mf)
            #pragma unroll
            for (int nt = 0; nt < 4; ++nt)
                acc[mf][nt] = __builtin_amdgcn_mfma_f32_16x16x32_bf16(af[mf], bfr[nt], acc[mf][nt], 0, 0, 0);
    }

    // acc[mf][nt][r] is score at m-row = wm*64+mf*16+q*4+r, col = nbase+wn*64+nt*16+l16

    if (!WRITE_OUT) {
        // ---- per-row (max, sumexp) over this block's 128 cols, fully parallel
        #pragma unroll
        for (int mf = 0; mf < 4; ++mf) {
            #pragma unroll
            for (int r = 0; r < 4; ++r) {
                bool valid[4];
                #pragma unroll
                for (int nt = 0; nt < 4; ++nt)
                    valid[nt] = (nbase + wn * 64 + nt * 16 + l16) < V_COLS;
                float mx = -INFINITY;
                #pragma unroll
                for (int nt = 0; nt < 4; ++nt)
                    if (valid[nt]) mx = fmaxf(mx, acc[mf][nt][r]);
                #pragma unroll
                for (int d = 1; d < 16; d <<= 1) mx = fmaxf(mx, __shfl_xor(mx, d, 16));
                float s = 0.f;
                #pragma unroll
                for (int nt = 0; nt < 4; ++nt)
                    if (valid[nt]) s += __expf(acc[mf][nt][r] - mx);
                #pragma unroll
                for (int d = 1; d < 16; d <<= 1) s += __shfl_xor(s, d, 16);
                if (l16 == 0) stats[wn][wm * 64 + mf * 16 + q * 4 + r] = make_float2(mx, s);
            }
        }
        __syncthreads();
        if (tid < 128) {
            float2 p0 = stats[0][tid], p1 = stats[1][tid];
            float mm = fmaxf(p0.x, p1.x);
            float ss = p0.y * __expf(p0.x - mm) + p1.y * __expf(p1.x - mm);
            partials[(long)(mbase + tid) * NNB + blockIdx.x] = make_float2(mm, ss);
        }
    } else {
        // ---- write scores - lse; LDS roundtrip for coalesced 512B/row segments
        __syncthreads();                        // tiles dead; reuse smem as score buffer
        float* sbuf = (float*)smem;             // stride 132 floats/row (2-way-free banks)
        #pragma unroll
        for (int mf = 0; mf < 4; ++mf)
            #pragma unroll
            for (int nt = 0; nt < 4; ++nt)
                #pragma unroll
                for (int r = 0; r < 4; ++r)
                    sbuf[(wm * 64 + mf * 16 + q * 4 + r) * 132 + wn * 64 + nt * 16 + l16] = acc[mf][nt][r];
        __syncthreads();
        #pragma unroll 4
        for (int it = 0; it < 64; ++it) {
            int i = it * 256 + tid;
            int r = i >> 7, c = i & 127;
            int col = nbase + c;
            if (col < V_COLS)
                out[(size_t)(mbase + r) * V_COLS + col] = sbuf[r * 132 + c] - lsev[r];
        }
    }
}

// ---------------------------------------------------------------- merge per-block (m,s) partials -> lse[b]
__global__ void merge_lse_kernel(const float2* __restrict__ partials, float* __restrict__ lse) {
    int b = blockIdx.x;
    int tid = threadIdx.x;
    float m = -INFINITY, s = 0.f;
    for (int i = tid; i < NNB; i += 256) {
        float2 p = partials[(long)b * NNB + i];
        if (p.x > m) { s = s * __expf(m - p.x) + p.y; m = p.x; }
        else         { s += p.y * __expf(p.x - m); }
    }
    __shared__ float sm[256], ss[256];
    sm[tid] = m; ss[tid] = s;
    __syncthreads();
    for (int off = 128; off > 0; off >>= 1) {
        if (tid < off) {
            float m1 = sm[tid], s1 = ss[tid];
            float m2 = sm[tid + off], s2 = ss[tid + off];
            float mm = fmaxf(m1, m2);
            sm[tid] = mm;
            ss[tid] = s1 * __expf(m1 - mm) + s2 * __expf(m2 - mm);
        }
        __syncthreads();
    }
    if (tid == 0) lse[b] = sm[0] + __logf(ss[0]);
}

// ---------------------------------------------------------------- launch
extern "C" void kernel_launch(void* const* d_in, const int* in_sizes, int n_in,
                              void* d_out, int out_size, void* d_ws, size_t ws_size,
                              hipStream_t stream) {
    const float* xs     = (const float*)d_in[0];
    const float* metric = (const float*)d_in[1];
    const float* EMB    = (const float*)d_in[2];
    const float* NEG    = (const float*)d_in[3];
    float* out = (float*)d_out;

    char* ws = (char*)d_ws;
    // layout: idx[1024] | t bf16[1024*128] | neg bf16[VPAD*128] | partials float2[1024*NNB] | lse[1024]
    int*            idx      = (int*)ws;                               // 4096 B
    unsigned short* t        = (unsigned short*)(ws + 4096);           // 262144 B -> 266240
    unsigned short* neg16    = (unsigned short*)(ws + 266240);         // VPAD*128*2 = 12877824 -> 13144064
    float2*         partials = (float2*)(ws + 13144064);               // 1024*393*8 = 3219456 -> 16363520
    float*          lse      = (float*)(ws + 16363520);                // 4096 B

    {
        long n4 = (long)B_ROWS * V_COLS / 4;
        int blocks = (int)((n4 + 255) / 256);
        find_idx_kernel<<<blocks, 256, 0, stream>>>((const float4*)xs, idx);
    }
    cvt_bf16_kernel<<<(N4P + 255) / 256, 256, 0, stream>>>((const float4*)NEG, (ushort4*)neg16);
    compute_t_kernel<<<B_ROWS, E_DIM, 0, stream>>>(EMB, metric, idx, t);
    gemm_kernel<false><<<dim3(NNB, B_ROWS / BM), 256, 0, stream>>>(t, neg16, partials, nullptr, nullptr);
    merge_lse_kernel<<<B_ROWS, 256, 0, stream>>>(partials, lse);
    gemm_kernel<true><<<dim3(NNB, B_ROWS / BM), 256, 0, stream>>>(t, neg16, partials, lse, out);
}